// Round 3
// baseline (186.322 us; speedup 1.0000x reference)
//
#include <hip/hip_runtime.h>

// Bidirectional NN-MSE via MFMA, single fused kernel.
//   loss = w * mean_n min_j ||p_n - g_j||^2 + (1-w) * mean_m min_i ||g_m - p_i||^2
//
// d^2 = qq - 2 q.r + rr computed inside mfma_f32_32x32x16_bf16 (K=16) with a
// 2-term bf16 split per operand (products of bf16 are exact in fp32).
// ROLE SWAP vs round 2: refs are the A operand (rows), queries the B operand
// (columns). Each lane's 16 C-regs then belong to ONE query -> min over refs
// is an in-lane min3 tree; cross-lane tail is a single shfl_xor(32) + atomic.
//
// A-form (ref r):   [-2xh,-2xh,-2xl,-2xl, -2yh,-2yh,-2yl,-2yl,
//                    -2zh,-2zh,-2zl,-2zl,  rrh, rrl, 1, 1]
// B-form (query q): [ xh, xl, xh, xl,  yh, yl, yh, yl,
//                     zh, zl, zh, zl,  1, 1, qqh, qql]
// k-pairing: sum_k A[k]*B[k] = -2 q.r + rr + qq  (exact to split precision).

#define NPTS    16384
#define QT      4                 // query tiles (32 cols) per wave
#define SSPLIT  16                // ref-range splits
#define RBLK    (NPTS / SSPLIT)   // 1024 refs staged per block (32 KB LDS)
#define QBLK    (4 * QT * 32)     // 512 queries per block
#define NBLOCKS (2 * (NPTS / QBLK) * SSPLIT)  // 2*32*16 = 1024

typedef __attribute__((ext_vector_type(8)))  __bf16 bf16x8;
typedef __attribute__((ext_vector_type(16))) float  floatx16;

__device__ __forceinline__ unsigned f2key(float f) {
    unsigned b = __float_as_uint(f);
    return (b & 0x80000000u) ? ~b : (b | 0x80000000u);
}
__device__ __forceinline__ float key2f(unsigned k) {
    unsigned b = (k & 0x80000000u) ? (k & 0x7FFFFFFFu) : ~k;
    return __uint_as_float(b);
}
__device__ __forceinline__ float vmin16(floatx16 v) {
    float a = fminf(fminf(v[0], v[1]), fminf(v[2], v[3]));
    float b = fminf(fminf(v[4], v[5]), fminf(v[6], v[7]));
    float c = fminf(fminf(v[8], v[9]), fminf(v[10], v[11]));
    float d = fminf(fminf(v[12], v[13]), fminf(v[14], v[15]));
    return fminf(fminf(a, b), fminf(c, d));   // -> v_min3_f32 chains
}

union frag16 { __bf16 v[16]; uint4 q[2]; };

__global__ __launch_bounds__(256) void nn_fused_kernel(
    const float* __restrict__ pred, const float* __restrict__ gt,
    const float* __restrict__ weight, unsigned* __restrict__ keys,
    unsigned* __restrict__ counter, float* __restrict__ out)
{
    const int bx   = blockIdx.x;          // 0..1023
    const int qg   = bx & 63;             // 32 query-blocks x 2 dirs
    const int s    = bx >> 6;             // ref split 0..15
    const int dir  = qg >> 5;             // 0: Q=pred,R=gt ; 1: Q=gt,R=pred
    const int tid  = threadIdx.x;
    const int lane = tid & 63;
    const int wave = tid >> 6;
    const int lid  = lane & 31;
    const int half = lane >> 5;

    const float* __restrict__ Q = dir ? gt : pred;
    const float* __restrict__ R = dir ? pred : gt;
    unsigned* kout = keys + dir * NPTS;

    __shared__ uint4 ldsA[RBLK * 2];      // [tile][half][lid] -> conflict-free

    // ---- stage ref fragments into LDS (built on the fly) ----
    const int rbase = s * RBLK;
    for (int j = tid; j < RBLK; j += 256) {
        const float x = R[(rbase + j) * 3 + 0];
        const float y = R[(rbase + j) * 3 + 1];
        const float z = R[(rbase + j) * 3 + 2];
        const float rr = x * x + y * y + z * z;
        const __bf16 xh = (__bf16)x, yh = (__bf16)y, zh = (__bf16)z;
        const __bf16 xl = (__bf16)(x - (float)xh);
        const __bf16 yl = (__bf16)(y - (float)yh);
        const __bf16 zl = (__bf16)(z - (float)zh);
        const __bf16 rh = (__bf16)rr;
        const __bf16 rl = (__bf16)(rr - (float)rh);
        const __bf16 one = (__bf16)1.0f;
        const __bf16 m2xh = (__bf16)(-2.0f * (float)xh), m2xl = (__bf16)(-2.0f * (float)xl);
        const __bf16 m2yh = (__bf16)(-2.0f * (float)yh), m2yl = (__bf16)(-2.0f * (float)yl);
        const __bf16 m2zh = (__bf16)(-2.0f * (float)zh), m2zl = (__bf16)(-2.0f * (float)zl);
        frag16 A;
        A.v[0] = m2xh; A.v[1]  = m2xh; A.v[2]  = m2xl; A.v[3]  = m2xl;
        A.v[4] = m2yh; A.v[5]  = m2yh; A.v[6]  = m2yl; A.v[7]  = m2yl;
        A.v[8] = m2zh; A.v[9]  = m2zh; A.v[10] = m2zl; A.v[11] = m2zl;
        A.v[12] = rh;  A.v[13] = rl;   A.v[14] = one;  A.v[15] = one;
        const int tile = j >> 5, l = j & 31;
        ldsA[tile * 64 + l]      = A.q[0];   // half 0 slots (k=0..7)
        ldsA[tile * 64 + 32 + l] = A.q[1];   // half 1 slots (k=8..15)
    }

    // ---- build query B-fragments in registers ----
    const int qbase = (qg & 31) * QBLK + wave * (QT * 32);
    bf16x8 bq[QT];
    float mn[QT];
#pragma unroll
    for (int qt = 0; qt < QT; ++qt) {
        const int p = qbase + qt * 32 + lid;
        const float x = Q[p * 3 + 0], y = Q[p * 3 + 1], z = Q[p * 3 + 2];
        const float qq = x * x + y * y + z * z;
        const __bf16 xh = (__bf16)x, yh = (__bf16)y, zh = (__bf16)z;
        const __bf16 xl = (__bf16)(x - (float)xh);
        const __bf16 yl = (__bf16)(y - (float)yh);
        const __bf16 zl = (__bf16)(z - (float)zh);
        const __bf16 qh = (__bf16)qq;
        const __bf16 ql = (__bf16)(qq - (float)qh);
        const __bf16 one = (__bf16)1.0f;
        frag16 B;
        B.v[0] = xh;  B.v[1]  = xl;  B.v[2]  = xh;  B.v[3]  = xl;
        B.v[4] = yh;  B.v[5]  = yl;  B.v[6]  = yh;  B.v[7]  = yl;
        B.v[8] = zh;  B.v[9]  = zl;  B.v[10] = zh;  B.v[11] = zl;
        B.v[12] = one; B.v[13] = one; B.v[14] = qh; B.v[15] = ql;
        bq[qt] = __builtin_bit_cast(bf16x8, B.q[half]);
        mn[qt] = 3.4e38f;
    }

    floatx16 zero;
#pragma unroll
    for (int k = 0; k < 16; ++k) zero[k] = 0.0f;

    __syncthreads();

    // ---- hot loop: LDS-only, 2 ref tiles per iteration ----
#pragma unroll 2
    for (int t = 0; t < RBLK / 32; t += 2) {
        const bf16x8 a0 = __builtin_bit_cast(bf16x8, ldsA[t * 64 + half * 32 + lid]);
        const bf16x8 a1 = __builtin_bit_cast(bf16x8, ldsA[(t + 1) * 64 + half * 32 + lid]);
#pragma unroll
        for (int qt = 0; qt < QT; ++qt) {
            floatx16 d0 = __builtin_amdgcn_mfma_f32_32x32x16_bf16(a0, bq[qt], zero, 0, 0, 0);
            floatx16 d1 = __builtin_amdgcn_mfma_f32_32x32x16_bf16(a1, bq[qt], zero, 0, 0, 0);
            mn[qt] = fminf(mn[qt], fminf(vmin16(d0), vmin16(d1)));
        }
    }

    // ---- tail: one shuffle + one atomic per query ----
#pragma unroll
    for (int qt = 0; qt < QT; ++qt) {
        const float v = fminf(mn[qt], __shfl_xor(mn[qt], 32));
        if (half == 0)
            atomicMin(&kout[qbase + qt * 32 + lid], f2key(v));
    }

    // ---- done-counter: last block reduces the keys and writes the loss ----
    __threadfence();
    __syncthreads();
    __shared__ unsigned slast;
    if (tid == 0) slast = atomicAdd(counter, 1);
    __syncthreads();
    if (slast == NBLOCKS - 1) {
        __threadfence();
        float s0 = 0.f, s1 = 0.f;
        for (int i = tid; i < NPTS; i += 256) {
            s0 += key2f(__hip_atomic_load(&keys[i], __ATOMIC_RELAXED,
                                          __HIP_MEMORY_SCOPE_AGENT));
            s1 += key2f(__hip_atomic_load(&keys[NPTS + i], __ATOMIC_RELAXED,
                                          __HIP_MEMORY_SCOPE_AGENT));
        }
        for (int off = 32; off; off >>= 1) {
            s0 += __shfl_down(s0, off);
            s1 += __shfl_down(s1, off);
        }
        __shared__ float w0[4], w1[4];
        if ((tid & 63) == 0) { w0[tid >> 6] = s0; w1[tid >> 6] = s1; }
        __syncthreads();
        if (tid == 0) {
            float a = w0[0] + w0[1] + w0[2] + w0[3];
            float b = w1[0] + w1[1] + w1[2] + w1[3];
            const float wgt = weight[0];
            const float inv = 1.0f / (3.0f * (float)NPTS);
            out[0] = wgt * (a * inv) + (1.0f - wgt) * (b * inv);
        }
    }
}

extern "C" void kernel_launch(void* const* d_in, const int* in_sizes, int n_in,
                              void* d_out, int out_size, void* d_ws, size_t ws_size,
                              hipStream_t stream) {
    const float* pred   = (const float*)d_in[0];
    const float* gt     = (const float*)d_in[1];
    const float* weight = (const float*)d_in[2];

    // ws: [keys: 2*NPTS u32][counter: 1 u32]
    unsigned* keys    = (unsigned*)d_ws;
    unsigned* counter = keys + 2 * NPTS;

    hipMemsetAsync(keys, 0xFF, (size_t)2 * NPTS * sizeof(unsigned), stream);
    hipMemsetAsync(counter, 0, sizeof(unsigned), stream);

    nn_fused_kernel<<<NBLOCKS, 256, 0, stream>>>(pred, gt, weight, keys,
                                                 counter, (float*)d_out);
}

// Round 4
// 87.655 us; speedup vs baseline: 2.1256x; 2.1256x over previous
//
#include <hip/hip_runtime.h>

// Bidirectional NN-MSE via MFMA, thrash-free version.
//   loss = w * mean_n min_j ||p_n - g_j||^2 + (1-w) * mean_m min_i ||g_m - p_i||^2
//
// d^2 = qq - 2 q.r + rr computed inside mfma_f32_32x32x16_bf16 (K=16) with a
// 2-term bf16 split per operand (bf16 x bf16 products are exact in fp32;
// only split-truncation error ~1e-5 remains, verified absmax 0 in R2/R3).
//
// Orientation: refs = A (rows), queries = B (cols). Each lane's 16 C-regs all
// belong to one query column; min over ref tiles is accumulated ELEMENTWISE
// (16 independent v_min3 chains -> full ILP), tree-reduced once at the end.
//
// NO device-scope atomics/fences in the main kernel (R3's 100x HBM over-fetch
// came from per-block __threadfence + atomicMin L2 writebacks): each block
// plain-stores partial mins to a private ws slice; a tiny second kernel
// min-combines the 16 ref-splits and accumulates the weighted sum.

#define NPTS   16384
#define QT     2                  // query tiles (32 cols) per wave
#define QBLK   (4 * QT * 32)      // 256 queries per block
#define QCH    (NPTS / QBLK)      // 64 query chunks
#define SSPLIT 16                 // ref splits
#define RBLK   (NPTS / SSPLIT)    // 1024 refs staged per block (32 KB LDS)
#define NB1    (2 * QCH * SSPLIT) // 2048 blocks

typedef __attribute__((ext_vector_type(8)))  __bf16 bf16x8;
typedef __attribute__((ext_vector_type(16))) float  floatx16;

union frag16 { __bf16 v[16]; uint4 q[2]; };

__device__ __forceinline__ float vmin16(floatx16 v) {
    float a = fminf(fminf(v[0], v[1]), v[2]);
    float b = fminf(fminf(v[3], v[4]), v[5]);
    float c = fminf(fminf(v[6], v[7]), v[8]);
    float d = fminf(fminf(v[9], v[10]), v[11]);
    float e = fminf(fminf(v[12], v[13]), fminf(v[14], v[15]));
    return fminf(fminf(fminf(a, b), fminf(c, d)), e);
}

__global__ __launch_bounds__(256) void nn_part_kernel(
    const float* __restrict__ pred, const float* __restrict__ gt,
    float* __restrict__ partial)
{
    const int bx   = blockIdx.x;           // 0..NB1-1
    const int dir  = bx >> 10;             // 0: Q=pred,R=gt ; 1: Q=gt,R=pred
    const int qc   = (bx & 1023) >> 4;     // 0..63
    const int s    = bx & 15;              // 0..15
    const int tid  = threadIdx.x;
    const int lane = tid & 63;
    const int wave = tid >> 6;
    const int lid  = lane & 31;
    const int half = lane >> 5;

    const float* __restrict__ Q = dir ? gt : pred;
    const float* __restrict__ R = dir ? pred : gt;

    __shared__ uint4 ldsA[RBLK * 2];       // [tile][half][lid], 32 KB

    // ---- stage ref A-fragments into LDS ----
    const int rbase = s * RBLK;
    for (int j = tid; j < RBLK; j += 256) {
        const float x = R[(rbase + j) * 3 + 0];
        const float y = R[(rbase + j) * 3 + 1];
        const float z = R[(rbase + j) * 3 + 2];
        const float rr = x * x + y * y + z * z;
        const __bf16 xh = (__bf16)x, yh = (__bf16)y, zh = (__bf16)z;
        const __bf16 xl = (__bf16)(x - (float)xh);
        const __bf16 yl = (__bf16)(y - (float)yh);
        const __bf16 zl = (__bf16)(z - (float)zh);
        const __bf16 rh = (__bf16)rr;
        const __bf16 rl = (__bf16)(rr - (float)rh);
        const __bf16 one = (__bf16)1.0f;
        frag16 A;
        A.v[0]  = (__bf16)(-2.0f * (float)xh); A.v[1]  = A.v[0];
        A.v[2]  = (__bf16)(-2.0f * (float)xl); A.v[3]  = A.v[2];
        A.v[4]  = (__bf16)(-2.0f * (float)yh); A.v[5]  = A.v[4];
        A.v[6]  = (__bf16)(-2.0f * (float)yl); A.v[7]  = A.v[6];
        A.v[8]  = (__bf16)(-2.0f * (float)zh); A.v[9]  = A.v[8];
        A.v[10] = (__bf16)(-2.0f * (float)zl); A.v[11] = A.v[10];
        A.v[12] = rh;  A.v[13] = rl;  A.v[14] = one;  A.v[15] = one;
        const int tile = j >> 5, l = j & 31;
        ldsA[tile * 64 + l]      = A.q[0];   // k = 0..7
        ldsA[tile * 64 + 32 + l] = A.q[1];   // k = 8..15
    }

    // ---- query B-fragments in registers ----
    const int qbase = qc * QBLK + wave * (QT * 32);
    bf16x8 bq[QT];
#pragma unroll
    for (int qt = 0; qt < QT; ++qt) {
        const int p = qbase + qt * 32 + lid;
        const float x = Q[p * 3 + 0], y = Q[p * 3 + 1], z = Q[p * 3 + 2];
        const float qq = x * x + y * y + z * z;
        const __bf16 xh = (__bf16)x, yh = (__bf16)y, zh = (__bf16)z;
        const __bf16 xl = (__bf16)(x - (float)xh);
        const __bf16 yl = (__bf16)(y - (float)yh);
        const __bf16 zl = (__bf16)(z - (float)zh);
        const __bf16 qh = (__bf16)qq;
        const __bf16 ql = (__bf16)(qq - (float)qh);
        const __bf16 one = (__bf16)1.0f;
        frag16 B;
        B.v[0] = xh;  B.v[1]  = xl;  B.v[2]  = xh;  B.v[3]  = xl;
        B.v[4] = yh;  B.v[5]  = yl;  B.v[6]  = yh;  B.v[7]  = yl;
        B.v[8] = zh;  B.v[9]  = zl;  B.v[10] = zh;  B.v[11] = zl;
        B.v[12] = one; B.v[13] = one; B.v[14] = qh;  B.v[15] = ql;
        bq[qt] = __builtin_bit_cast(bf16x8, B.q[half]);
    }

    floatx16 zero;
#pragma unroll
    for (int k = 0; k < 16; ++k) zero[k] = 0.0f;
    floatx16 mnv[QT];
#pragma unroll
    for (int qt = 0; qt < QT; ++qt)
#pragma unroll
        for (int k = 0; k < 16; ++k) mnv[qt][k] = 3.4e38f;

    __syncthreads();

    // ---- hot loop: LDS-only, 2 ref tiles x QT MFMAs per iteration ----
#pragma unroll 2
    for (int t = 0; t < RBLK / 32; t += 2) {
        const bf16x8 a0 = __builtin_bit_cast(bf16x8, ldsA[t * 64 + half * 32 + lid]);
        const bf16x8 a1 = __builtin_bit_cast(bf16x8, ldsA[(t + 1) * 64 + half * 32 + lid]);
#pragma unroll
        for (int qt = 0; qt < QT; ++qt) {
            floatx16 d0 = __builtin_amdgcn_mfma_f32_32x32x16_bf16(a0, bq[qt], zero, 0, 0, 0);
            floatx16 d1 = __builtin_amdgcn_mfma_f32_32x32x16_bf16(a1, bq[qt], zero, 0, 0, 0);
#pragma unroll
            for (int k = 0; k < 16; ++k)   // 16 independent v_min3 chains
                mnv[qt][k] = fminf(fminf(mnv[qt][k], d0[k]), d1[k]);
        }
    }

    // ---- tail: in-lane tree + one shuffle, then PLAIN coalesced store ----
    float* pout = partial + ((size_t)((dir * QCH + qc) * SSPLIT + s)) * QBLK
                + wave * (QT * 32);
#pragma unroll
    for (int qt = 0; qt < QT; ++qt) {
        float v = vmin16(mnv[qt]);
        v = fminf(v, __shfl_xor(v, 32));
        if (half == 0) pout[qt * 32 + lid] = v;
    }
}

// Combine: min over the 16 ref-splits per query, weighted sum into out.
__global__ __launch_bounds__(256) void nn_combine_kernel(
    const float* __restrict__ partial, const float* __restrict__ weight,
    float* __restrict__ out)
{
    const int b   = blockIdx.x;        // 0..127 : dir = b>>6, qc = b&63
    const int dir = b >> 6;
    const int qc  = b & 63;
    const int t   = threadIdx.x;

    const float* p = partial + ((size_t)((dir * QCH + qc) * SSPLIT)) * QBLK;
    float v = p[t];
#pragma unroll
    for (int s = 1; s < SSPLIT; ++s)
        v = fminf(v, p[s * QBLK + t]);

    // block sum of v
    for (int off = 32; off; off >>= 1) v += __shfl_down(v, off);
    __shared__ float ws[4];
    if ((t & 63) == 0) ws[t >> 6] = v;
    __syncthreads();
    if (t == 0) {
        const float sum = ws[0] + ws[1] + ws[2] + ws[3];
        const float wgt = weight[0];
        const float scale = (dir ? (1.0f - wgt) : wgt) / (3.0f * (float)NPTS);
        atomicAdd(out, sum * scale);
    }
}

extern "C" void kernel_launch(void* const* d_in, const int* in_sizes, int n_in,
                              void* d_out, int out_size, void* d_ws, size_t ws_size,
                              hipStream_t stream) {
    const float* pred   = (const float*)d_in[0];
    const float* gt     = (const float*)d_in[1];
    const float* weight = (const float*)d_in[2];
    float* partial = (float*)d_ws;     // 2*QCH*SSPLIT*QBLK floats = 2 MB

    hipMemsetAsync(d_out, 0, sizeof(float), stream);
    nn_part_kernel<<<NB1, 256, 0, stream>>>(pred, gt, partial);
    nn_combine_kernel<<<2 * QCH, 256, 0, stream>>>(partial, weight, (float*)d_out);
}